// Round 1
// baseline (141.106 us; speedup 1.0000x reference)
//
#include <hip/hip_runtime.h>
#include <math.h>

#define NR 8
#define NB 8
#define NH 32
#define NKVH 8
#define NG 4
#define ND 128
#define NDV 128
#define NPAGE 2048
#define NSPLIT 2
#define NPART (NR*NSPLIT)
#define QSCALE 0.088388347648318447f  /* 1/sqrt(128) */

__device__ __forceinline__ float half_reduce(float v) {
  // xor masks < 32 keep the reduction inside each 32-lane half of the wave64
  v += __shfl_xor(v, 16);
  v += __shfl_xor(v, 8);
  v += __shfl_xor(v, 4);
  v += __shfl_xor(v, 2);
  v += __shfl_xor(v, 1);
  return v;
}

// Online softmax update for one head: branchy rescale (rare on real data).
#define ONLINE(mm, ll, aa, ss)                                              \
  do {                                                                      \
    if ((ss) > (mm)) {                                                      \
      const float sc_ = __expf((mm) - (ss));                                \
      (mm) = (ss);                                                          \
      (ll) = (ll) * sc_ + 1.0f;                                             \
      (aa).x = (aa).x * sc_ + v4.x;                                         \
      (aa).y = (aa).y * sc_ + v4.y;                                         \
      (aa).z = (aa).z * sc_ + v4.z;                                         \
      (aa).w = (aa).w * sc_ + v4.w;                                         \
    } else {                                                                \
      const float p_ = __expf((ss) - (mm));                                 \
      (ll) += p_;                                                           \
      (aa).x += p_ * v4.x;                                                  \
      (aa).y += p_ * v4.y;                                                  \
      (aa).z += p_ * v4.z;                                                  \
      (aa).w += p_ * v4.w;                                                  \
    }                                                                       \
  } while (0)

__global__ __launch_bounds__(256, 4) void attn_partial(
    const float* __restrict__ q,
    const float* __restrict__ k_cache,
    const float* __restrict__ v_cache,
    const int* __restrict__ kv_lens,
    const int* __restrict__ block_table,
    float* __restrict__ ws_out,   // [NPART][NB][NKVH][NG][NDV]
    float* __restrict__ ws_lse)   // [NPART][NB][NKVH][NG]
{
  const int bid = blockIdx.x;
  const int sp  = bid & (NSPLIT - 1);
  const int kvh = (bid / NSPLIT) & (NKVH - 1);
  const int b   = (bid / (NSPLIT * NKVH)) & (NB - 1);
  const int r   = bid / (NSPLIT * NKVH * NB);

  const int tid = threadIdx.x;
  const int gid = tid >> 5;   // 8 half-wave groups per block
  const int sub = tid & 31;   // lane within group; owns dims 4*sub..4*sub+3

  const int len   = kv_lens[r * NB + b];
  const int chunk = (len + NSPLIT - 1) / NSPLIT;
  const int lo    = sp * chunk;
  const int hi    = min(len, lo + chunk);

  const int* bt = block_table + (r * NB + b) * NPAGE;
  const float* Kr = k_cache + (size_t)r * NPAGE * (NKVH * ND)  + kvh * ND  + 4 * sub;
  const float* Vr = v_cache + (size_t)r * NPAGE * (NKVH * NDV) + kvh * NDV + 4 * sub;

  const float* qb = q + (b * NH + kvh * NG) * ND + 4 * sub;
  float4 q0 = *(const float4*)(qb + 0 * ND);
  float4 q1 = *(const float4*)(qb + 1 * ND);
  float4 q2 = *(const float4*)(qb + 2 * ND);
  float4 q3 = *(const float4*)(qb + 3 * ND);
  q0.x *= QSCALE; q0.y *= QSCALE; q0.z *= QSCALE; q0.w *= QSCALE;
  q1.x *= QSCALE; q1.y *= QSCALE; q1.z *= QSCALE; q1.w *= QSCALE;
  q2.x *= QSCALE; q2.y *= QSCALE; q2.z *= QSCALE; q2.w *= QSCALE;
  q3.x *= QSCALE; q3.y *= QSCALE; q3.z *= QSCALE; q3.w *= QSCALE;

  float m0 = -INFINITY, m1 = -INFINITY, m2 = -INFINITY, m3 = -INFINITY;
  float l0 = 0.f, l1 = 0.f, l2 = 0.f, l3 = 0.f;
  float4 a0 = {0.f, 0.f, 0.f, 0.f};
  float4 a1 = {0.f, 0.f, 0.f, 0.f};
  float4 a2 = {0.f, 0.f, 0.f, 0.f};
  float4 a3 = {0.f, 0.f, 0.f, 0.f};

  for (int n = lo + gid; n < hi; n += 8) {
    const int page = bt[n];  // same addr across the 32-lane group -> broadcast
    const float4 k4 = *(const float4*)(Kr + (size_t)page * (NKVH * ND));
    const float4 v4 = *(const float4*)(Vr + (size_t)page * (NKVH * NDV));

    float s0 = k4.x * q0.x + k4.y * q0.y + k4.z * q0.z + k4.w * q0.w;
    float s1 = k4.x * q1.x + k4.y * q1.y + k4.z * q1.z + k4.w * q1.w;
    float s2 = k4.x * q2.x + k4.y * q2.y + k4.z * q2.z + k4.w * q2.w;
    float s3 = k4.x * q3.x + k4.y * q3.y + k4.z * q3.z + k4.w * q3.w;
    s0 = half_reduce(s0);
    s1 = half_reduce(s1);
    s2 = half_reduce(s2);
    s3 = half_reduce(s3);

    ONLINE(m0, l0, a0, s0);
    ONLINE(m1, l1, a1, s1);
    ONLINE(m2, l2, a2, s2);
    ONLINE(m3, l3, a3, s3);
  }

  // ---- merge the 8 groups via LDS ----
  __shared__ float lds_m[8][NG];
  __shared__ float lds_l[8][NG];
  __shared__ float lds_a[8][NG][NDV];
  if (sub == 0) {
    lds_m[gid][0] = m0; lds_m[gid][1] = m1; lds_m[gid][2] = m2; lds_m[gid][3] = m3;
    lds_l[gid][0] = l0; lds_l[gid][1] = l1; lds_l[gid][2] = l2; lds_l[gid][3] = l3;
  }
  {
    float* p0 = &lds_a[gid][0][4 * sub];
    p0[0] = a0.x; p0[1] = a0.y; p0[2] = a0.z; p0[3] = a0.w;
    float* p1 = &lds_a[gid][1][4 * sub];
    p1[0] = a1.x; p1[1] = a1.y; p1[2] = a1.z; p1[3] = a1.w;
    float* p2 = &lds_a[gid][2][4 * sub];
    p2[0] = a2.x; p2[1] = a2.y; p2[2] = a2.z; p2[3] = a2.w;
    float* p3 = &lds_a[gid][3][4 * sub];
    p3[0] = a3.x; p3[1] = a3.y; p3[2] = a3.z; p3[3] = a3.w;
  }
  __syncthreads();

  __shared__ float Mg[NG], Lg[NG];
  if (tid < NG) {
    float M = -INFINITY;
    for (int p = 0; p < 8; ++p) M = fmaxf(M, lds_m[p][tid]);
    float L = 0.f;
    if (M > -INFINITY) {
      for (int p = 0; p < 8; ++p) L += lds_l[p][tid] * __expf(lds_m[p][tid] - M);
    }
    Mg[tid] = M; Lg[tid] = L;
  }
  __syncthreads();

  const int pi = r * NSPLIT + sp;
  const size_t pbase = (((size_t)pi * NB + b) * NKVH + kvh) * NG;
  for (int idx = tid; idx < NG * NDV; idx += 256) {
    const int g = idx >> 7;
    const int d = idx & (NDV - 1);
    const float M = Mg[g];
    const float L = Lg[g];
    float acc = 0.f;
    if (L > 0.f) {
      for (int p = 0; p < 8; ++p) acc += lds_a[p][g][d] * __expf(lds_m[p][g] - M);
      acc /= L;
    }
    ws_out[(pbase + g) * NDV + d] = acc;
    if (d == 0) ws_lse[pbase + g] = (L > 0.f) ? (M + __logf(L)) : -1e30f;
  }
}

// One block per (b, kvh, g); logsumexp-weighted combine over NPART partials.
__global__ __launch_bounds__(128) void attn_combine(
    const float* __restrict__ ws_out,
    const float* __restrict__ ws_lse,
    float* __restrict__ out)
{
  const int bkg = blockIdx.x;      // = (b*NKVH + kvh)*NG + g ; out row = bkg
  const int d   = threadIdx.x;     // 0..127

  float lse[NPART];
  float m = -INFINITY;
#pragma unroll
  for (int p = 0; p < NPART; ++p) {
    lse[p] = ws_lse[p * (NB * NKVH * NG) + bkg];
    m = fmaxf(m, lse[p]);
  }
  float denom = 0.f, acc = 0.f;
#pragma unroll
  for (int p = 0; p < NPART; ++p) {
    const float e = __expf(lse[p] - m);
    denom += e;
    acc += e * ws_out[((size_t)p * (NB * NKVH * NG) + bkg) * NDV + d];
  }
  out[(size_t)bkg * NDV + d] = (denom > 0.f) ? (acc / denom) : 0.f;
}

extern "C" void kernel_launch(void* const* d_in, const int* in_sizes, int n_in,
                              void* d_out, int out_size, void* d_ws, size_t ws_size,
                              hipStream_t stream) {
  const float* q        = (const float*)d_in[0];
  const float* k_cache  = (const float*)d_in[1];
  const float* v_cache  = (const float*)d_in[2];
  const int*   kv_lens  = (const int*)d_in[3];
  const int*   bt       = (const int*)d_in[4];
  float* out = (float*)d_out;

  float* ws_out = (float*)d_ws;
  float* ws_lse = ws_out + (size_t)NPART * NB * NKVH * NG * NDV;

  attn_partial<<<NR * NB * NKVH * NSPLIT, 256, 0, stream>>>(
      q, k_cache, v_cache, kv_lens, bt, ws_out, ws_lse);
  attn_combine<<<NB * NKVH * NG, NDV, 0, stream>>>(ws_out, ws_lse, out);
}